// Round 6
// baseline (131.709 us; speedup 1.0000x reference)
//
#include <hip/hip_runtime.h>
#include <hip/hip_bf16.h>

typedef unsigned short u16;
typedef unsigned int u32;
typedef __bf16 bf16_t;
typedef bf16_t bf16x8 __attribute__((ext_vector_type(8)));
typedef float f32x4 __attribute__((ext_vector_type(4)));

#define NTOT 4096   // H*W*D
#define CCH 128
#define QSCL 0.25503486703f   // log2(e)/sqrt(32)

__device__ __forceinline__ float bf2f(u16 x) {
    return __uint_as_float(((u32)x) << 16);
}
// packed f32x2 -> bf16x2 (v_cvt_pk_bf16_f32), RNE
__device__ __forceinline__ u32 pkbf(float a, float b) {
    __hip_bfloat162 h = __float22bfloat162_rn(make_float2(a, b));
    u32 r; __builtin_memcpy(&r, &h, 4); return r;
}
__device__ __forceinline__ u16 f2bf(float a) {
    return (u16)(pkbf(a, a) & 0xffffu);
}
// V fragment: two 8B halves 32B apart (virtual-k layout, direct from global)
__device__ __forceinline__ bf16x8 ldv(const u16* p) {
    uint2 lo = *(const uint2*)(p);
    uint2 hi = *(const uint2*)(p + 16);
    uint4 u = {lo.x, lo.y, hi.x, hi.y};
    bf16x8 r; __builtin_memcpy(&r, &u, 16); return r;
}

// ---------------------------------------------------------------------------
// Kernel 1: QKV projections, MFMA, full 128 out-channels per block.
// Weight cast fp32->bf16 folded into LDS staging (no prep kernel).
// grid (64 nt, 3 p, 2 b), block 256. Wave w covers n-rows w*16+l16, all c.
// Q,K stored [bh][n][d]; V stored [b*128+c][n].
// ---------------------------------------------------------------------------
__global__ __launch_bounds__(256, 4) void proj_kernel(
    const float* __restrict__ xq, const float* __restrict__ xkv,
    const float* __restrict__ Wq, const float* __restrict__ bq,
    const float* __restrict__ Wk, const float* __restrict__ bk_,
    const float* __restrict__ Wv, const float* __restrict__ bv_,
    u16* __restrict__ Qt, u16* __restrict__ Kt, u16* __restrict__ Vn)
{
    const int nt = blockIdx.x, p = blockIdx.y, b = blockIdx.z;
    const float* X    = (p == 0) ? xq : xkv;
    const float* Wf   = (p == 0) ? Wq : (p == 1) ? Wk : Wv;
    const float* bias = (p == 0) ? bq : (p == 1) ? bk_ : bv_;
    const float s = (p == 0) ? QSCL : 1.0f;   // Q pre-scale folded into W & b
    const int n0 = nt * 64;
    const int tid = threadIdx.x;

    __shared__ u16 Xt[64 * 128];        // B tile [n][ci], swizzled
    __shared__ u16 Wl[128 * 136];       // A tile [c][ci], pad stride 136

    // stage X (fp32 -> bf16), 16 ci-chunks of 8 per n
    #pragma unroll
    for (int k = 0; k < 4; ++k) {
        int n = tid & 63;
        int c = (tid >> 6) + k * 4;     // ci-chunk 0..15
        float f[8];
        #pragma unroll
        for (int j = 0; j < 8; ++j)
            f[j] = X[((size_t)(b * CCH) + 8 * c + j) * NTOT + n0 + n];
        uint4 vv = {pkbf(f[0], f[1]), pkbf(f[2], f[3]), pkbf(f[4], f[5]), pkbf(f[6], f[7])};
        *(uint4*)(Xt + n * 128 + ((c ^ (n & 7)) * 8)) = vv;
    }
    // stage W fp32 -> bf16: 128 rows x 16 chunks of 8 = 2048 b128 chunks
    #pragma unroll
    for (int k = 0; k < 8; ++k) {
        int id = tid + k * 256;         // 0..2047
        int row = id >> 4;              // 0..127
        int off = (id & 15) * 8;        // 0..120
        const float* wsrc = Wf + row * 128 + off;
        float4 wa = *(const float4*)(wsrc);
        float4 wc = *(const float4*)(wsrc + 4);
        uint4 vv = {pkbf(wa.x * s, wa.y * s), pkbf(wa.z * s, wa.w * s),
                    pkbf(wc.x * s, wc.y * s), pkbf(wc.z * s, wc.w * s)};
        *(uint4*)(Wl + row * 136 + off) = vv;
    }
    __syncthreads();

    const int wave = tid >> 6, lane = tid & 63;
    const int quad = lane >> 4, l16 = lane & 15;
    f32x4 acc[8];
    #pragma unroll
    for (int cf = 0; cf < 8; ++cf) acc[cf] = (f32x4){0.f, 0.f, 0.f, 0.f};

    #pragma unroll
    for (int kk = 0; kk < 4; ++kk) {
        bf16x8 bx = *(const bf16x8*)(Xt + (wave * 16 + l16) * 128 +
                                     (((kk * 4 + quad) ^ (l16 & 7)) * 8));
        #pragma unroll
        for (int cf = 0; cf < 8; ++cf) {
            bf16x8 aw = *(const bf16x8*)(Wl + (cf * 16 + l16) * 136 + kk * 32 + quad * 8);
            acc[cf] = __builtin_amdgcn_mfma_f32_16x16x32_bf16(aw, bx, acc[cf], 0, 0, 0);
        }
    }

    const int n = n0 + wave * 16 + l16;
    #pragma unroll
    for (int cf = 0; cf < 8; ++cf) {
        float4 b4 = *(const float4*)(bias + cf * 16 + quad * 4);
        float v0 = acc[cf][0] + b4.x * s;
        float v1 = acc[cf][1] + b4.y * s;
        float v2 = acc[cf][2] + b4.z * s;
        float v3 = acc[cf][3] + b4.w * s;
        if (p < 2) {
            const int h = cf >> 1;
            const int d0 = (cf & 1) * 16 + quad * 4;
            u16* dst = (p == 0 ? Qt : Kt) + ((size_t)(b * 4 + h) * NTOT + n) * 32 + d0;
            uint2 vv = {pkbf(v0, v1), pkbf(v2, v3)};
            *(uint2*)dst = vv;
        } else {
            int c = cf * 16 + quad * 4;
            u16* dst = Vn + (size_t)(b * CCH + c) * NTOT + n;
            dst[0 * NTOT] = f2bf(v0); dst[1 * NTOT] = f2bf(v1);
            dst[2 * NTOT] = f2bf(v2); dst[3 * NTOT] = f2bf(v3);
        }
    }
}

// ---------------------------------------------------------------------------
// Kernel 2: flash attention, 64 q per wave (4 groups), 256 q per block.
// NO LDS, NO barriers: K and V fragments loaded DIRECTLY from global into
// registers (addresses are the same permutation the old LDS staging+read
// realized; every access covers full 64B cache lines, L1/L2-resident).
// Explicit next-iteration register prefetch. P never touches LDS
// (virtual-k V layout; lane's own exp2 outputs are its B-fragment).
// grid (16 qt, 4 kc, 8 bh). Round-5 lesson: per-iter staging+barrier cost
// is q-independent -> remove the barrier structure, not the q-count.
// ---------------------------------------------------------------------------
__global__ __launch_bounds__(256, 2) void flash_attn_kernel(
    const u16* __restrict__ Qt, const u16* __restrict__ Kt,
    const u16* __restrict__ Vn, u16* __restrict__ pO, float* __restrict__ pL)
{
    const int bh = blockIdx.z, kc = blockIdx.y;
    const int wave = threadIdx.x >> 6, lane = threadIdx.x & 63;
    const int q = lane >> 4, l16 = lane & 15;
    const int q0w = blockIdx.x * 256 + wave * 64;

    const u16* Qbh = Qt + (size_t)bh * NTOT * 32;
    const u16* Kbh = Kt + (size_t)bh * NTOT * 32;
    const u16* Vg  = Vn + ((size_t)((bh >> 2) * CCH + (bh & 3) * 32)) * NTOT;

    const int kbase = kc * 1024;

    bf16x8 bq[4];
    #pragma unroll
    for (int g = 0; g < 4; ++g)
        bq[g] = *(const bf16x8*)(Qbh + (size_t)(q0w + g * 16 + l16) * 32 + q * 8);

    // per-lane source bases
    // K fragment t: row kbase+it*64+t*16+l16, d = q*8..q*8+7  (16B)
    const u16* kp  = Kbh + (size_t)(kbase + l16) * 32 + q * 8;
    // V fragment r: d = (r&1)*16+l16, n = kbase+it*64+(r>>1)*32+q*4 (+16 hi)
    const u16* vp0 = Vg + (size_t)l16 * NTOT + kbase + q * 4;
    const u16* vp1 = vp0 + (size_t)16 * NTOT;

    f32x4 o[4][2];
    #pragma unroll
    for (int g = 0; g < 4; ++g) {
        o[g][0] = (f32x4){0,0,0,0};
        o[g][1] = (f32x4){0,0,0,0};
    }
    const f32x4 zero = {0,0,0,0};
    float lp[4] = {0.f, 0.f, 0.f, 0.f};

    bf16x8 ak[4], av[4];
    #pragma unroll
    for (int t = 0; t < 4; ++t)
        ak[t] = *(const bf16x8*)(kp + (size_t)(t * 16) * 32);
    #pragma unroll
    for (int r = 0; r < 4; ++r)
        av[r] = ldv(((r & 1) ? vp1 : vp0) + (r >> 1) * 32);

    for (int it = 0; it < 16; ++it) {
        bf16x8 nak[4], nav[4];
        if (it < 15) {
            const int m1 = (it + 1) * 64;
            #pragma unroll
            for (int t = 0; t < 4; ++t)
                nak[t] = *(const bf16x8*)(kp + (size_t)(m1 + t * 16) * 32);
            #pragma unroll
            for (int r = 0; r < 4; ++r)
                nav[r] = ldv(((r & 1) ? vp1 : vp0) + m1 + (r >> 1) * 32);
        }
        // S for all 4 q-groups (K fragments shared)
        f32x4 s[4][4];
        #pragma unroll
        for (int t = 0; t < 4; ++t) {
            #pragma unroll
            for (int g = 0; g < 4; ++g)
                s[g][t] = __builtin_amdgcn_mfma_f32_16x16x32_bf16(ak[t], bq[g], zero, 0, 0, 0);
        }
        // per group: exp2 -> pack in-register -> PV (no LDS round-trip)
        #pragma unroll
        for (int g = 0; g < 4; ++g) {
            float e[4][4];
            #pragma unroll
            for (int t = 0; t < 4; ++t) {
                e[t][0] = __builtin_amdgcn_exp2f(s[g][t][0]);
                e[t][1] = __builtin_amdgcn_exp2f(s[g][t][1]);
                e[t][2] = __builtin_amdgcn_exp2f(s[g][t][2]);
                e[t][3] = __builtin_amdgcn_exp2f(s[g][t][3]);
                lp[g] += (e[t][0] + e[t][1]) + (e[t][2] + e[t][3]);
            }
            uint4 u0 = {pkbf(e[0][0], e[0][1]), pkbf(e[0][2], e[0][3]),
                        pkbf(e[1][0], e[1][1]), pkbf(e[1][2], e[1][3])};
            uint4 u1 = {pkbf(e[2][0], e[2][1]), pkbf(e[2][2], e[2][3]),
                        pkbf(e[3][0], e[3][1]), pkbf(e[3][2], e[3][3])};
            bf16x8 pb0, pb1;
            __builtin_memcpy(&pb0, &u0, 16);
            __builtin_memcpy(&pb1, &u1, 16);
            o[g][0] = __builtin_amdgcn_mfma_f32_16x16x32_bf16(av[0], pb0, o[g][0], 0, 0, 0);
            o[g][1] = __builtin_amdgcn_mfma_f32_16x16x32_bf16(av[1], pb0, o[g][1], 0, 0, 0);
            o[g][0] = __builtin_amdgcn_mfma_f32_16x16x32_bf16(av[2], pb1, o[g][0], 0, 0, 0);
            o[g][1] = __builtin_amdgcn_mfma_f32_16x16x32_bf16(av[3], pb1, o[g][1], 0, 0, 0);
        }
        if (it < 15) {
            #pragma unroll
            for (int t = 0; t < 4; ++t) ak[t] = nak[t];
            #pragma unroll
            for (int r = 0; r < 4; ++r) av[r] = nav[r];
        }
    }

    #pragma unroll
    for (int g = 0; g < 4; ++g) {
        lp[g] += __shfl_xor(lp[g], 16);
        lp[g] += __shfl_xor(lp[g], 32);
        const size_t ob = ((size_t)(kc * 8 + bh) * NTOT + q0w + g * 16 + l16) * 32 + q * 4;
        uint2 w0 = {pkbf(o[g][0][0], o[g][0][1]), pkbf(o[g][0][2], o[g][0][3])};
        uint2 w1 = {pkbf(o[g][1][0], o[g][1][1]), pkbf(o[g][1][2], o[g][1][3])};
        *(uint2*)(pO + ob)      = w0;
        *(uint2*)(pO + ob + 16) = w1;
        if (q == 0)
            pL[(size_t)(kc * 8 + bh) * NTOT + q0w + g * 16 + l16] = lp[g];
    }
}

// ---------------------------------------------------------------------------
// Kernel 3: fused combine + out-projection + bias + residual -> res fp32,
// plus partial sum/sumsq. grid (64 nt, 2 ct64, 2 b), block 256.
// Wo cast fp32->bf16 folded into LDS staging. NO grid barrier (round-1
// lesson: device-scope single-line barrier across 8 XCDs costs ~40 us).
// ---------------------------------------------------------------------------
__global__ __launch_bounds__(256, 4) void outproj_kernel(
    const float* __restrict__ xq,
    const u16* __restrict__ pO, const float* __restrict__ pL,
    const float* __restrict__ Wo, const float* __restrict__ bo,
    float* __restrict__ res, float* __restrict__ partS, float* __restrict__ partQ)
{
    const int nt = blockIdx.x, ct = blockIdx.y, b = blockIdx.z;
    const int n0 = nt * 64;
    const int tid = threadIdx.x;

    __shared__ u16 Xt[64 * 128];        // combined attn tile [n][ci], swizzled
    __shared__ u16 Wl[64 * 136];        // Wo rows ct*64.., pad stride 136

    #pragma unroll
    for (int k = 0; k < 4; ++k) {
        int cid = tid + k * 256;
        int n = cid >> 4;               // 0..63
        int ch = cid & 15;              // ci-chunk: h = ch>>2, d0 = (ch&3)*8
        int bh = b * 4 + (ch >> 2);
        int d0 = (ch & 3) * 8;
        float l = 0.f;
        float v[8];
        #pragma unroll
        for (int j = 0; j < 8; ++j) v[j] = 0.f;
        #pragma unroll
        for (int kcc = 0; kcc < 4; ++kcc) {
            const size_t nrow = (size_t)(kcc * 8 + bh) * NTOT + n0 + n;
            l += pL[nrow];
            uint4 u = *(const uint4*)(pO + nrow * 32 + d0);
            const u32 uu[4] = {u.x, u.y, u.z, u.w};
            #pragma unroll
            for (int j = 0; j < 4; ++j) {
                v[2 * j]     += bf2f((u16)(uu[j] & 0xffffu));
                v[2 * j + 1] += bf2f((u16)(uu[j] >> 16));
            }
        }
        const float inv = 1.0f / l;
        uint4 vv = {pkbf(v[0] * inv, v[1] * inv), pkbf(v[2] * inv, v[3] * inv),
                    pkbf(v[4] * inv, v[5] * inv), pkbf(v[6] * inv, v[7] * inv)};
        *(uint4*)(Xt + n * 128 + ((ch ^ (n & 7)) * 8)) = vv;
    }
    // stage Wo rows ct*64..ct*64+63 fp32 -> bf16: 64 rows x 16 chunks
    #pragma unroll
    for (int k = 0; k < 4; ++k) {
        int id = tid + k * 256;         // 0..1023
        int row = id >> 4;              // 0..63
        int off = (id & 15) * 8;        // 0..120
        const float* wsrc = Wo + (size_t)(ct * 64 + row) * 128 + off;
        float4 wa = *(const float4*)(wsrc);
        float4 wc = *(const float4*)(wsrc + 4);
        uint4 vv = {pkbf(wa.x, wa.y), pkbf(wa.z, wa.w),
                    pkbf(wc.x, wc.y), pkbf(wc.z, wc.w)};
        *(uint4*)(Wl + row * 136 + off) = vv;
    }
    __syncthreads();

    const int wave = tid >> 6, lane = tid & 63;
    const int quad = lane >> 4, l16 = lane & 15;
    f32x4 acc[4];
    #pragma unroll
    for (int cf = 0; cf < 4; ++cf) acc[cf] = (f32x4){0.f, 0.f, 0.f, 0.f};

    #pragma unroll
    for (int kk = 0; kk < 4; ++kk) {
        bf16x8 bx = *(const bf16x8*)(Xt + (wave * 16 + l16) * 128 +
                                     (((kk * 4 + quad) ^ (l16 & 7)) * 8));
        #pragma unroll
        for (int cf = 0; cf < 4; ++cf) {
            bf16x8 aw = *(const bf16x8*)(Wl + (cf * 16 + l16) * 136 + kk * 32 + quad * 8);
            acc[cf] = __builtin_amdgcn_mfma_f32_16x16x32_bf16(aw, bx, acc[cf], 0, 0, 0);
        }
    }

    const int n = n0 + wave * 16 + l16;
    const int tile = nt * 4 + wave;
    #pragma unroll
    for (int cf = 0; cf < 4; ++cf) {
        float4 b4 = *(const float4*)(bo + ct * 64 + cf * 16 + quad * 4);
        const float bb[4] = {b4.x, b4.y, b4.z, b4.w};
        float sv[4], qv[4];
        #pragma unroll
        for (int r = 0; r < 4; ++r) {
            int c = ct * 64 + cf * 16 + quad * 4 + r;
            float v = acc[cf][r] + bb[r] + xq[(size_t)(b * CCH + c) * NTOT + n];
            res[(size_t)(b * CCH + c) * NTOT + n] = v;
            sv[r] = v;
            qv[r] = v * v;
        }
        #pragma unroll
        for (int off = 1; off < 16; off <<= 1) {
            #pragma unroll
            for (int r = 0; r < 4; ++r) {
                sv[r] += __shfl_xor(sv[r], off);
                qv[r] += __shfl_xor(qv[r], off);
            }
        }
        if (l16 == 0) {
            #pragma unroll
            for (int r = 0; r < 4; ++r) {
                int c = ct * 64 + cf * 16 + quad * 4 + r;
                partS[(size_t)(b * CCH + c) * 256 + tile] = sv[r];
                partQ[(size_t)(b * CCH + c) * 256 + tile] = qv[r];
            }
        }
    }
}

// ---------------------------------------------------------------------------
// Kernel 4: reduce partials, InstanceNorm, fp32 store. grid (128, 2).
// ---------------------------------------------------------------------------
__global__ __launch_bounds__(256) void norm_kernel(
    const float* __restrict__ res, const float* __restrict__ partS,
    const float* __restrict__ partQ, float* __restrict__ out)
{
    const int c = blockIdx.x, b = blockIdx.y;
    const int tid = threadIdx.x;
    const size_t row = (size_t)(b * CCH + c);
    __shared__ float rs[4], rq[4];
    float s = partS[row * 256 + tid];
    float q = partQ[row * 256 + tid];
    #pragma unroll
    for (int off = 1; off < 64; off <<= 1) {
        s += __shfl_xor(s, off);
        q += __shfl_xor(q, off);
    }
    const int wv = tid >> 6, ln = tid & 63;
    if (ln == 0) { rs[wv] = s; rq[wv] = q; }
    __syncthreads();
    float ts = rs[0] + rs[1] + rs[2] + rs[3];
    float tq = rq[0] + rq[1] + rq[2] + rq[3];
    float mu  = ts * (1.0f / 4096.0f);
    float var = tq * (1.0f / 4096.0f) - mu * mu;
    float inv = rsqrtf(var + 1e-5f);
    const size_t base = row * NTOT;
    #pragma unroll
    for (int j = 0; j < 4; ++j) {
        int n = tid * 4 + j * 1024;
        float4 v = *(const float4*)(res + base + n);
        float4 o;
        o.x = (v.x - mu) * inv; o.y = (v.y - mu) * inv;
        o.z = (v.z - mu) * inv; o.w = (v.w - mu) * inv;
        *(float4*)(out + base + n) = o;
    }
}

extern "C" void kernel_launch(void* const* d_in, const int* in_sizes, int n_in,
                              void* d_out, int out_size, void* d_ws, size_t ws_size,
                              hipStream_t stream)
{
    const float* xq  = (const float*)d_in[0];
    const float* xkv = (const float*)d_in[1];
    const float* Wq  = (const float*)d_in[2];
    const float* bq  = (const float*)d_in[3];
    const float* Wk  = (const float*)d_in[4];
    const float* bk  = (const float*)d_in[5];
    const float* Wv  = (const float*)d_in[6];
    const float* bv  = (const float*)d_in[7];
    const float* Wo  = (const float*)d_in[8];
    const float* bo  = (const float*)d_in[9];
    float* out = (float*)d_out;

    char* ws = (char*)d_ws;
    const size_t MB = (size_t)1 << 20;
    u16* Qt = (u16*)(ws + 0 * MB);            // 2 MB [bh][n][d]
    u16* Kt = (u16*)(ws + 2 * MB);            // 2 MB
    u16* Vn = (u16*)(ws + 4 * MB);            // 2 MB [b*128+c][n]
    u16* pO = (u16*)(ws + 6 * MB);            // 8 MB [kc][bh][n][d]
    float* pL = (float*)(ws + 14 * MB);       // 512 KB [kc][bh][n]
    float* res   = (float*)(ws + 16 * MB);    // 4 MB
    float* partS = (float*)(ws + 20 * MB);            // 256 KB
    float* partQ = (float*)(ws + 20 * MB + 262144);   // 256 KB

    proj_kernel<<<dim3(64, 3, 2), 256, 0, stream>>>(xq, xkv, Wq, bq, Wk, bk, Wv, bv, Qt, Kt, Vn);
    flash_attn_kernel<<<dim3(16, 4, 8), 256, 0, stream>>>(Qt, Kt, Vn, pO, pL);
    outproj_kernel<<<dim3(64, 2, 2), 256, 0, stream>>>(xq, pO, pL, Wo, bo, res, partS, partQ);
    norm_kernel<<<dim3(128, 2), 256, 0, stream>>>(res, partS, partQ, out);
}

// Round 7
// 121.039 us; speedup vs baseline: 1.0882x; 1.0882x over previous
//
#include <hip/hip_runtime.h>
#include <hip/hip_bf16.h>

typedef unsigned short u16;
typedef unsigned int u32;
typedef __bf16 bf16_t;
typedef bf16_t bf16x8 __attribute__((ext_vector_type(8)));
typedef float f32x4 __attribute__((ext_vector_type(4)));

#define NTOT 4096   // H*W*D
#define CCH 128
#define QSCL 0.25503486703f   // log2(e)/sqrt(32)

__device__ __forceinline__ float bf2f(u16 x) {
    return __uint_as_float(((u32)x) << 16);
}
// packed f32x2 -> bf16x2 (v_cvt_pk_bf16_f32), RNE
__device__ __forceinline__ u32 pkbf(float a, float b) {
    __hip_bfloat162 h = __float22bfloat162_rn(make_float2(a, b));
    u32 r; __builtin_memcpy(&r, &h, 4); return r;
}
__device__ __forceinline__ u16 f2bf(float a) {
    return (u16)(pkbf(a, a) & 0xffffu);
}

// ---------------------------------------------------------------------------
// Kernel 1: QKV projections, MFMA, full 128 out-channels per block.
// Weight cast fp32->bf16 folded into LDS staging (no prep kernel).
// grid (64 nt, 3 p, 2 b), block 256. Wave w covers n-rows w*16+l16, all c.
// Q,K stored [bh][n][d]; V stored [b*128+c][n].
// ---------------------------------------------------------------------------
__global__ __launch_bounds__(256, 4) void proj_kernel(
    const float* __restrict__ xq, const float* __restrict__ xkv,
    const float* __restrict__ Wq, const float* __restrict__ bq,
    const float* __restrict__ Wk, const float* __restrict__ bk_,
    const float* __restrict__ Wv, const float* __restrict__ bv_,
    u16* __restrict__ Qt, u16* __restrict__ Kt, u16* __restrict__ Vn)
{
    const int nt = blockIdx.x, p = blockIdx.y, b = blockIdx.z;
    const float* X    = (p == 0) ? xq : xkv;
    const float* Wf   = (p == 0) ? Wq : (p == 1) ? Wk : Wv;
    const float* bias = (p == 0) ? bq : (p == 1) ? bk_ : bv_;
    const float s = (p == 0) ? QSCL : 1.0f;   // Q pre-scale folded into W & b
    const int n0 = nt * 64;
    const int tid = threadIdx.x;

    __shared__ u16 Xt[64 * 128];        // B tile [n][ci], swizzled
    __shared__ u16 Wl[128 * 136];       // A tile [c][ci], pad stride 136

    // stage X (fp32 -> bf16), 16 ci-chunks of 8 per n
    #pragma unroll
    for (int k = 0; k < 4; ++k) {
        int n = tid & 63;
        int c = (tid >> 6) + k * 4;     // ci-chunk 0..15
        float f[8];
        #pragma unroll
        for (int j = 0; j < 8; ++j)
            f[j] = X[((size_t)(b * CCH) + 8 * c + j) * NTOT + n0 + n];
        uint4 vv = {pkbf(f[0], f[1]), pkbf(f[2], f[3]), pkbf(f[4], f[5]), pkbf(f[6], f[7])};
        *(uint4*)(Xt + n * 128 + ((c ^ (n & 7)) * 8)) = vv;
    }
    // stage W fp32 -> bf16: 128 rows x 16 chunks of 8 = 2048 b128 chunks
    #pragma unroll
    for (int k = 0; k < 8; ++k) {
        int id = tid + k * 256;         // 0..2047
        int row = id >> 4;              // 0..127
        int off = (id & 15) * 8;        // 0..120
        const float* wsrc = Wf + row * 128 + off;
        float4 wa = *(const float4*)(wsrc);
        float4 wc = *(const float4*)(wsrc + 4);
        uint4 vv = {pkbf(wa.x * s, wa.y * s), pkbf(wa.z * s, wa.w * s),
                    pkbf(wc.x * s, wc.y * s), pkbf(wc.z * s, wc.w * s)};
        *(uint4*)(Wl + row * 136 + off) = vv;
    }
    __syncthreads();

    const int wave = tid >> 6, lane = tid & 63;
    const int quad = lane >> 4, l16 = lane & 15;
    f32x4 acc[8];
    #pragma unroll
    for (int cf = 0; cf < 8; ++cf) acc[cf] = (f32x4){0.f, 0.f, 0.f, 0.f};

    #pragma unroll
    for (int kk = 0; kk < 4; ++kk) {
        bf16x8 bx = *(const bf16x8*)(Xt + (wave * 16 + l16) * 128 +
                                     (((kk * 4 + quad) ^ (l16 & 7)) * 8));
        #pragma unroll
        for (int cf = 0; cf < 8; ++cf) {
            bf16x8 aw = *(const bf16x8*)(Wl + (cf * 16 + l16) * 136 + kk * 32 + quad * 8);
            acc[cf] = __builtin_amdgcn_mfma_f32_16x16x32_bf16(aw, bx, acc[cf], 0, 0, 0);
        }
    }

    const int n = n0 + wave * 16 + l16;
    #pragma unroll
    for (int cf = 0; cf < 8; ++cf) {
        float4 b4 = *(const float4*)(bias + cf * 16 + quad * 4);
        float v0 = acc[cf][0] + b4.x * s;
        float v1 = acc[cf][1] + b4.y * s;
        float v2 = acc[cf][2] + b4.z * s;
        float v3 = acc[cf][3] + b4.w * s;
        if (p < 2) {
            const int h = cf >> 1;
            const int d0 = (cf & 1) * 16 + quad * 4;
            u16* dst = (p == 0 ? Qt : Kt) + ((size_t)(b * 4 + h) * NTOT + n) * 32 + d0;
            uint2 vv = {pkbf(v0, v1), pkbf(v2, v3)};
            *(uint2*)dst = vv;
        } else {
            int c = cf * 16 + quad * 4;
            u16* dst = Vn + (size_t)(b * CCH + c) * NTOT + n;
            dst[0 * NTOT] = f2bf(v0); dst[1 * NTOT] = f2bf(v1);
            dst[2 * NTOT] = f2bf(v2); dst[3 * NTOT] = f2bf(v3);
        }
    }
}

// ---------------------------------------------------------------------------
// Kernel 2: flash attention, 64 q per wave (4 groups), 256 q per block.
// kc split 8 (512 k per block). ENTIRE K/V slice staged to LDS ONCE
// (32 KB + 32 KB, single __syncthreads), then 8 barrier-free compute
// iterations with tile-ahead ds_read prefetch. Tile layouts identical to
// the verified R4 mappings (K: [t][slot64][8]; V: virtual-k regions).
// P never touches LDS (lane's own exp2 outputs are its B-fragment).
// grid (16 qt, 8 kc, 8 bh), 2 blocks/CU (64 KB LDS).
// R6 lesson: direct-global fragments cost 64-bit addr VALU + L2 latency;
// R4 lesson: per-iter barrier drain serializes. This removes both.
// ---------------------------------------------------------------------------
__global__ __launch_bounds__(256, 2) void flash_attn_kernel(
    const u16* __restrict__ Qt, const u16* __restrict__ Kt,
    const u16* __restrict__ Vn, u16* __restrict__ pO, float* __restrict__ pL)
{
    const int bh = blockIdx.z, kc = blockIdx.y;
    const int wave = threadIdx.x >> 6, lane = threadIdx.x & 63;
    const int q = lane >> 4, l16 = lane & 15;
    const int q0w = blockIdx.x * 256 + wave * 64;

    const u16* Qbh = Qt + (size_t)bh * NTOT * 32;
    const u16* Kbh = Kt + (size_t)bh * NTOT * 32;
    const u16* Vg  = Vn + ((size_t)((bh >> 2) * CCH + (bh & 3) * 32)) * NTOT;

    __shared__ u16 Ksh[8 * 2048];   // [tile m][t(4)][slot 64][8]   32 KB
    __shared__ u16 Vsh[8 * 2048];   // [tile m][region(4)][virt-k]  32 KB

    const int kbase = kc * 512;

    bf16x8 bq[4];
    #pragma unroll
    for (int g = 0; g < 4; ++g)
        bq[g] = *(const bf16x8*)(Qbh + (size_t)(q0w + g * 16 + l16) * 32 + q * 8);

    // ---- stage full 512-k slice (8 tiles), one barrier ----
    {
        const size_t kst = (size_t)(kbase + wave * 16 + l16) * 32 + q * 8;
        const size_t vst = (size_t)((wave & 1) * 16 + l16) * NTOT + kbase +
                           (wave >> 1) * 32 + q * 8;
        const int kds = wave * 512 + lane * 8;
        const int vds = wave * 512 + (q & 1) * 256 + l16 * 8 + (q >> 1) * 4;
        #pragma unroll
        for (int m = 0; m < 8; ++m) {
            uint4 kr = *(const uint4*)(Kbh + kst + m * 2048);   // 64 rows x 32 d
            uint4 vr = *(const uint4*)(Vg + vst + m * 64);
            *(uint4*)(&Ksh[m * 2048 + kds]) = kr;
            uint2 va = {kr.x, kr.y};   // placeholder to keep regs tight
            va.x = vr.x; va.y = vr.y;
            uint2 vb = {vr.z, vr.w};
            *(uint2*)(&Vsh[m * 2048 + vds])       = va;
            *(uint2*)(&Vsh[m * 2048 + vds + 128]) = vb;
        }
    }
    __syncthreads();

    f32x4 o[4][2];
    #pragma unroll
    for (int g = 0; g < 4; ++g) {
        o[g][0] = (f32x4){0,0,0,0};
        o[g][1] = (f32x4){0,0,0,0};
    }
    const f32x4 zero = {0,0,0,0};
    float lp[4] = {0.f, 0.f, 0.f, 0.f};

    const int frd = lane * 8;           // fragment read offset within region
    bf16x8 ak[4], av[4];
    #pragma unroll
    for (int t = 0; t < 4; ++t) {
        ak[t] = *(const bf16x8*)(&Ksh[t * 512 + frd]);
        av[t] = *(const bf16x8*)(&Vsh[t * 512 + frd]);
    }

    for (int m = 0; m < 8; ++m) {
        bf16x8 nak[4], nav[4];
        if (m < 7) {
            const int nb = (m + 1) * 2048;
            #pragma unroll
            for (int t = 0; t < 4; ++t) {
                nak[t] = *(const bf16x8*)(&Ksh[nb + t * 512 + frd]);
                nav[t] = *(const bf16x8*)(&Vsh[nb + t * 512 + frd]);
            }
        }
        // S for all 4 q-groups (K fragments shared)
        f32x4 s[4][4];
        #pragma unroll
        for (int t = 0; t < 4; ++t) {
            #pragma unroll
            for (int g = 0; g < 4; ++g)
                s[g][t] = __builtin_amdgcn_mfma_f32_16x16x32_bf16(ak[t], bq[g], zero, 0, 0, 0);
        }
        // per group: exp2 -> pack in-register -> PV (no LDS round-trip)
        #pragma unroll
        for (int g = 0; g < 4; ++g) {
            float e[4][4];
            #pragma unroll
            for (int t = 0; t < 4; ++t) {
                e[t][0] = __builtin_amdgcn_exp2f(s[g][t][0]);
                e[t][1] = __builtin_amdgcn_exp2f(s[g][t][1]);
                e[t][2] = __builtin_amdgcn_exp2f(s[g][t][2]);
                e[t][3] = __builtin_amdgcn_exp2f(s[g][t][3]);
                lp[g] += (e[t][0] + e[t][1]) + (e[t][2] + e[t][3]);
            }
            uint4 u0 = {pkbf(e[0][0], e[0][1]), pkbf(e[0][2], e[0][3]),
                        pkbf(e[1][0], e[1][1]), pkbf(e[1][2], e[1][3])};
            uint4 u1 = {pkbf(e[2][0], e[2][1]), pkbf(e[2][2], e[2][3]),
                        pkbf(e[3][0], e[3][1]), pkbf(e[3][2], e[3][3])};
            bf16x8 pb0, pb1;
            __builtin_memcpy(&pb0, &u0, 16);
            __builtin_memcpy(&pb1, &u1, 16);
            o[g][0] = __builtin_amdgcn_mfma_f32_16x16x32_bf16(av[0], pb0, o[g][0], 0, 0, 0);
            o[g][1] = __builtin_amdgcn_mfma_f32_16x16x32_bf16(av[1], pb0, o[g][1], 0, 0, 0);
            o[g][0] = __builtin_amdgcn_mfma_f32_16x16x32_bf16(av[2], pb1, o[g][0], 0, 0, 0);
            o[g][1] = __builtin_amdgcn_mfma_f32_16x16x32_bf16(av[3], pb1, o[g][1], 0, 0, 0);
        }
        if (m < 7) {
            #pragma unroll
            for (int t = 0; t < 4; ++t) { ak[t] = nak[t]; av[t] = nav[t]; }
        }
    }

    #pragma unroll
    for (int g = 0; g < 4; ++g) {
        lp[g] += __shfl_xor(lp[g], 16);
        lp[g] += __shfl_xor(lp[g], 32);
        const size_t ob = ((size_t)(kc * 8 + bh) * NTOT + q0w + g * 16 + l16) * 32 + q * 4;
        uint2 w0 = {pkbf(o[g][0][0], o[g][0][1]), pkbf(o[g][0][2], o[g][0][3])};
        uint2 w1 = {pkbf(o[g][1][0], o[g][1][1]), pkbf(o[g][1][2], o[g][1][3])};
        *(uint2*)(pO + ob)      = w0;
        *(uint2*)(pO + ob + 16) = w1;
        if (q == 0)
            pL[(size_t)(kc * 8 + bh) * NTOT + q0w + g * 16 + l16] = lp[g];
    }
}

// ---------------------------------------------------------------------------
// Kernel 3: fused combine (8 kc partials) + out-projection + bias + residual
// -> res fp32, plus partial sum/sumsq. grid (64 nt, 2 ct64, 2 b), block 256.
// Wo cast fp32->bf16 folded into LDS staging. NO grid barrier (round-1
// lesson: device-scope single-line barrier across 8 XCDs costs ~40 us).
// ---------------------------------------------------------------------------
__global__ __launch_bounds__(256, 4) void outproj_kernel(
    const float* __restrict__ xq,
    const u16* __restrict__ pO, const float* __restrict__ pL,
    const float* __restrict__ Wo, const float* __restrict__ bo,
    float* __restrict__ res, float* __restrict__ partS, float* __restrict__ partQ)
{
    const int nt = blockIdx.x, ct = blockIdx.y, b = blockIdx.z;
    const int n0 = nt * 64;
    const int tid = threadIdx.x;

    __shared__ u16 Xt[64 * 128];        // combined attn tile [n][ci], swizzled
    __shared__ u16 Wl[64 * 136];        // Wo rows ct*64.., pad stride 136

    #pragma unroll
    for (int k = 0; k < 4; ++k) {
        int cid = tid + k * 256;
        int n = cid >> 4;               // 0..63
        int ch = cid & 15;              // ci-chunk: h = ch>>2, d0 = (ch&3)*8
        int bh = b * 4 + (ch >> 2);
        int d0 = (ch & 3) * 8;
        float l = 0.f;
        float v[8];
        #pragma unroll
        for (int j = 0; j < 8; ++j) v[j] = 0.f;
        #pragma unroll
        for (int kcc = 0; kcc < 8; ++kcc) {
            const size_t nrow = (size_t)(kcc * 8 + bh) * NTOT + n0 + n;
            l += pL[nrow];
            uint4 u = *(const uint4*)(pO + nrow * 32 + d0);
            const u32 uu[4] = {u.x, u.y, u.z, u.w};
            #pragma unroll
            for (int j = 0; j < 4; ++j) {
                v[2 * j]     += bf2f((u16)(uu[j] & 0xffffu));
                v[2 * j + 1] += bf2f((u16)(uu[j] >> 16));
            }
        }
        const float inv = 1.0f / l;
        uint4 vv = {pkbf(v[0] * inv, v[1] * inv), pkbf(v[2] * inv, v[3] * inv),
                    pkbf(v[4] * inv, v[5] * inv), pkbf(v[6] * inv, v[7] * inv)};
        *(uint4*)(Xt + n * 128 + ((ch ^ (n & 7)) * 8)) = vv;
    }
    // stage Wo rows ct*64..ct*64+63 fp32 -> bf16: 64 rows x 16 chunks
    #pragma unroll
    for (int k = 0; k < 4; ++k) {
        int id = tid + k * 256;         // 0..1023
        int row = id >> 4;              // 0..63
        int off = (id & 15) * 8;        // 0..120
        const float* wsrc = Wo + (size_t)(ct * 64 + row) * 128 + off;
        float4 wa = *(const float4*)(wsrc);
        float4 wc = *(const float4*)(wsrc + 4);
        uint4 vv = {pkbf(wa.x, wa.y), pkbf(wa.z, wa.w),
                    pkbf(wc.x, wc.y), pkbf(wc.z, wc.w)};
        *(uint4*)(Wl + row * 136 + off) = vv;
    }
    __syncthreads();

    const int wave = tid >> 6, lane = tid & 63;
    const int quad = lane >> 4, l16 = lane & 15;
    f32x4 acc[4];
    #pragma unroll
    for (int cf = 0; cf < 4; ++cf) acc[cf] = (f32x4){0.f, 0.f, 0.f, 0.f};

    #pragma unroll
    for (int kk = 0; kk < 4; ++kk) {
        bf16x8 bx = *(const bf16x8*)(Xt + (wave * 16 + l16) * 128 +
                                     (((kk * 4 + quad) ^ (l16 & 7)) * 8));
        #pragma unroll
        for (int cf = 0; cf < 4; ++cf) {
            bf16x8 aw = *(const bf16x8*)(Wl + (cf * 16 + l16) * 136 + kk * 32 + quad * 8);
            acc[cf] = __builtin_amdgcn_mfma_f32_16x16x32_bf16(aw, bx, acc[cf], 0, 0, 0);
        }
    }

    const int n = n0 + wave * 16 + l16;
    const int tile = nt * 4 + wave;
    #pragma unroll
    for (int cf = 0; cf < 4; ++cf) {
        float4 b4 = *(const float4*)(bo + ct * 64 + cf * 16 + quad * 4);
        const float bb[4] = {b4.x, b4.y, b4.z, b4.w};
        float sv[4], qv[4];
        #pragma unroll
        for (int r = 0; r < 4; ++r) {
            int c = ct * 64 + cf * 16 + quad * 4 + r;
            float v = acc[cf][r] + bb[r] + xq[(size_t)(b * CCH + c) * NTOT + n];
            res[(size_t)(b * CCH + c) * NTOT + n] = v;
            sv[r] = v;
            qv[r] = v * v;
        }
        #pragma unroll
        for (int off = 1; off < 16; off <<= 1) {
            #pragma unroll
            for (int r = 0; r < 4; ++r) {
                sv[r] += __shfl_xor(sv[r], off);
                qv[r] += __shfl_xor(qv[r], off);
            }
        }
        if (l16 == 0) {
            #pragma unroll
            for (int r = 0; r < 4; ++r) {
                int c = ct * 64 + cf * 16 + quad * 4 + r;
                partS[(size_t)(b * CCH + c) * 256 + tile] = sv[r];
                partQ[(size_t)(b * CCH + c) * 256 + tile] = qv[r];
            }
        }
    }
}

// ---------------------------------------------------------------------------
// Kernel 4: reduce partials, InstanceNorm, fp32 store. grid (128, 2).
// ---------------------------------------------------------------------------
__global__ __launch_bounds__(256) void norm_kernel(
    const float* __restrict__ res, const float* __restrict__ partS,
    const float* __restrict__ partQ, float* __restrict__ out)
{
    const int c = blockIdx.x, b = blockIdx.y;
    const int tid = threadIdx.x;
    const size_t row = (size_t)(b * CCH + c);
    __shared__ float rs[4], rq[4];
    float s = partS[row * 256 + tid];
    float q = partQ[row * 256 + tid];
    #pragma unroll
    for (int off = 1; off < 64; off <<= 1) {
        s += __shfl_xor(s, off);
        q += __shfl_xor(q, off);
    }
    const int wv = tid >> 6, ln = tid & 63;
    if (ln == 0) { rs[wv] = s; rq[wv] = q; }
    __syncthreads();
    float ts = rs[0] + rs[1] + rs[2] + rs[3];
    float tq = rq[0] + rq[1] + rq[2] + rq[3];
    float mu  = ts * (1.0f / 4096.0f);
    float var = tq * (1.0f / 4096.0f) - mu * mu;
    float inv = rsqrtf(var + 1e-5f);
    const size_t base = row * NTOT;
    #pragma unroll
    for (int j = 0; j < 4; ++j) {
        int n = tid * 4 + j * 1024;
        float4 v = *(const float4*)(res + base + n);
        float4 o;
        o.x = (v.x - mu) * inv; o.y = (v.y - mu) * inv;
        o.z = (v.z - mu) * inv; o.w = (v.w - mu) * inv;
        *(float4*)(out + base + n) = o;
    }
}

extern "C" void kernel_launch(void* const* d_in, const int* in_sizes, int n_in,
                              void* d_out, int out_size, void* d_ws, size_t ws_size,
                              hipStream_t stream)
{
    const float* xq  = (const float*)d_in[0];
    const float* xkv = (const float*)d_in[1];
    const float* Wq  = (const float*)d_in[2];
    const float* bq  = (const float*)d_in[3];
    const float* Wk  = (const float*)d_in[4];
    const float* bk  = (const float*)d_in[5];
    const float* Wv  = (const float*)d_in[6];
    const float* bv  = (const float*)d_in[7];
    const float* Wo  = (const float*)d_in[8];
    const float* bo  = (const float*)d_in[9];
    float* out = (float*)d_out;

    char* ws = (char*)d_ws;
    const size_t MB = (size_t)1 << 20;
    u16* Qt = (u16*)(ws + 0 * MB);            // 2 MB [bh][n][d]
    u16* Kt = (u16*)(ws + 2 * MB);            // 2 MB
    u16* Vn = (u16*)(ws + 4 * MB);            // 2 MB [b*128+c][n]
    u16* pO = (u16*)(ws + 6 * MB);            // 16 MB [kc8][bh][n][d]
    float* pL = (float*)(ws + 22 * MB);       // 1 MB [kc8][bh][n]
    float* res   = (float*)(ws + 23 * MB);    // 4 MB
    float* partS = (float*)(ws + 27 * MB);            // 256 KB
    float* partQ = (float*)(ws + 27 * MB + 262144);   // 256 KB

    proj_kernel<<<dim3(64, 3, 2), 256, 0, stream>>>(xq, xkv, Wq, bq, Wk, bk, Wv, bv, Qt, Kt, Vn);
    flash_attn_kernel<<<dim3(16, 8, 8), 256, 0, stream>>>(Qt, Kt, Vn, pO, pL);
    outproj_kernel<<<dim3(64, 2, 2), 256, 0, stream>>>(xq, pO, pL, Wo, bo, res, partS, partQ);
    norm_kernel<<<dim3(128, 2), 256, 0, stream>>>(res, partS, partQ, out);
}

// Round 8
// 120.150 us; speedup vs baseline: 1.0962x; 1.0074x over previous
//
#include <hip/hip_runtime.h>
#include <hip/hip_bf16.h>

typedef unsigned short u16;
typedef unsigned int u32;
typedef __bf16 bf16_t;
typedef bf16_t bf16x8 __attribute__((ext_vector_type(8)));
typedef float f32x4 __attribute__((ext_vector_type(4)));

#define NTOT 4096   // H*W*D
#define CCH 128
#define QSCL 0.25503486703f   // log2(e)/sqrt(32)

__device__ __forceinline__ float bf2f(u16 x) {
    return __uint_as_float(((u32)x) << 16);
}
// packed f32x2 -> bf16x2 (v_cvt_pk_bf16_f32), RNE
__device__ __forceinline__ u32 pkbf(float a, float b) {
    __hip_bfloat162 h = __float22bfloat162_rn(make_float2(a, b));
    u32 r; __builtin_memcpy(&r, &h, 4); return r;
}
__device__ __forceinline__ u16 f2bf(float a) {
    return (u16)(pkbf(a, a) & 0xffffu);
}

// ---------------------------------------------------------------------------
// Kernel 1: QKV projections, MFMA, full 128 out-channels per block.
// Weight cast fp32->bf16 folded into LDS staging (no prep kernel).
// grid (64 nt, 3 p, 2 b), block 256. Wave w covers n-rows w*16+l16, all c.
// Q,K stored [bh][n][d]; V stored [b*128+c][n].
// ---------------------------------------------------------------------------
__global__ __launch_bounds__(256, 4) void proj_kernel(
    const float* __restrict__ xq, const float* __restrict__ xkv,
    const float* __restrict__ Wq, const float* __restrict__ bq,
    const float* __restrict__ Wk, const float* __restrict__ bk_,
    const float* __restrict__ Wv, const float* __restrict__ bv_,
    u16* __restrict__ Qt, u16* __restrict__ Kt, u16* __restrict__ Vn)
{
    const int nt = blockIdx.x, p = blockIdx.y, b = blockIdx.z;
    const float* X    = (p == 0) ? xq : xkv;
    const float* Wf   = (p == 0) ? Wq : (p == 1) ? Wk : Wv;
    const float* bias = (p == 0) ? bq : (p == 1) ? bk_ : bv_;
    const float s = (p == 0) ? QSCL : 1.0f;   // Q pre-scale folded into W & b
    const int n0 = nt * 64;
    const int tid = threadIdx.x;

    __shared__ u16 Xt[64 * 128];        // B tile [n][ci], swizzled
    __shared__ u16 Wl[128 * 136];       // A tile [c][ci], pad stride 136

    // stage X (fp32 -> bf16), 16 ci-chunks of 8 per n
    #pragma unroll
    for (int k = 0; k < 4; ++k) {
        int n = tid & 63;
        int c = (tid >> 6) + k * 4;     // ci-chunk 0..15
        float f[8];
        #pragma unroll
        for (int j = 0; j < 8; ++j)
            f[j] = X[((size_t)(b * CCH) + 8 * c + j) * NTOT + n0 + n];
        uint4 vv = {pkbf(f[0], f[1]), pkbf(f[2], f[3]), pkbf(f[4], f[5]), pkbf(f[6], f[7])};
        *(uint4*)(Xt + n * 128 + ((c ^ (n & 7)) * 8)) = vv;
    }
    // stage W fp32 -> bf16: 128 rows x 16 chunks of 8 = 2048 b128 chunks
    #pragma unroll
    for (int k = 0; k < 8; ++k) {
        int id = tid + k * 256;         // 0..2047
        int row = id >> 4;              // 0..127
        int off = (id & 15) * 8;        // 0..120
        const float* wsrc = Wf + row * 128 + off;
        float4 wa = *(const float4*)(wsrc);
        float4 wc = *(const float4*)(wsrc + 4);
        uint4 vv = {pkbf(wa.x * s, wa.y * s), pkbf(wa.z * s, wa.w * s),
                    pkbf(wc.x * s, wc.y * s), pkbf(wc.z * s, wc.w * s)};
        *(uint4*)(Wl + row * 136 + off) = vv;
    }
    __syncthreads();

    const int wave = tid >> 6, lane = tid & 63;
    const int quad = lane >> 4, l16 = lane & 15;
    f32x4 acc[8];
    #pragma unroll
    for (int cf = 0; cf < 8; ++cf) acc[cf] = (f32x4){0.f, 0.f, 0.f, 0.f};

    #pragma unroll
    for (int kk = 0; kk < 4; ++kk) {
        bf16x8 bx = *(const bf16x8*)(Xt + (wave * 16 + l16) * 128 +
                                     (((kk * 4 + quad) ^ (l16 & 7)) * 8));
        #pragma unroll
        for (int cf = 0; cf < 8; ++cf) {
            bf16x8 aw = *(const bf16x8*)(Wl + (cf * 16 + l16) * 136 + kk * 32 + quad * 8);
            acc[cf] = __builtin_amdgcn_mfma_f32_16x16x32_bf16(aw, bx, acc[cf], 0, 0, 0);
        }
    }

    const int n = n0 + wave * 16 + l16;
    #pragma unroll
    for (int cf = 0; cf < 8; ++cf) {
        float4 b4 = *(const float4*)(bias + cf * 16 + quad * 4);
        float v0 = acc[cf][0] + b4.x * s;
        float v1 = acc[cf][1] + b4.y * s;
        float v2 = acc[cf][2] + b4.z * s;
        float v3 = acc[cf][3] + b4.w * s;
        if (p < 2) {
            const int h = cf >> 1;
            const int d0 = (cf & 1) * 16 + quad * 4;
            u16* dst = (p == 0 ? Qt : Kt) + ((size_t)(b * 4 + h) * NTOT + n) * 32 + d0;
            uint2 vv = {pkbf(v0, v1), pkbf(v2, v3)};
            *(uint2*)dst = vv;
        } else {
            int c = cf * 16 + quad * 4;
            u16* dst = Vn + (size_t)(b * CCH + c) * NTOT + n;
            dst[0 * NTOT] = f2bf(v0); dst[1 * NTOT] = f2bf(v1);
            dst[2 * NTOT] = f2bf(v2); dst[3 * NTOT] = f2bf(v3);
        }
    }
}

// ---------------------------------------------------------------------------
// Kernel 2: flash attention, 64 q per wave (4 groups), 256 q per block.
// kc split 4 (1024 k per block) processed as TWO 512-k stages:
// stage 8 tiles -> sync -> 8 barrier-free compute iters -> sync -> restage.
// 3 barriers per block total (R4: 16, R7: 1 but with 16 MB pO).
// Tile layouts identical to the verified R4 mappings (K: [t][slot64][8];
// V: virtual-k regions). P never touches LDS (lane's own exp2 outputs are
// its B-fragment). grid (16 qt, 4 kc, 8 bh), 64 KB LDS, 2 blocks/CU.
// R7 lesson: kc=8's extra 8 MB of pO ate the flash win in outproj.
// ---------------------------------------------------------------------------
__global__ __launch_bounds__(256, 2) void flash_attn_kernel(
    const u16* __restrict__ Qt, const u16* __restrict__ Kt,
    const u16* __restrict__ Vn, u16* __restrict__ pO, float* __restrict__ pL)
{
    const int bh = blockIdx.z, kc = blockIdx.y;
    const int wave = threadIdx.x >> 6, lane = threadIdx.x & 63;
    const int q = lane >> 4, l16 = lane & 15;
    const int q0w = blockIdx.x * 256 + wave * 64;

    const u16* Qbh = Qt + (size_t)bh * NTOT * 32;
    const u16* Kbh = Kt + (size_t)bh * NTOT * 32;
    const u16* Vg  = Vn + ((size_t)((bh >> 2) * CCH + (bh & 3) * 32)) * NTOT;

    __shared__ u16 Ksh[8 * 2048];   // [tile m][t(4)][slot 64][8]   32 KB
    __shared__ u16 Vsh[8 * 2048];   // [tile m][region(4)][virt-k]  32 KB

    const int kbase = kc * 1024;

    bf16x8 bq[4];
    #pragma unroll
    for (int g = 0; g < 4; ++g)
        bq[g] = *(const bf16x8*)(Qbh + (size_t)(q0w + g * 16 + l16) * 32 + q * 8);

    const size_t kst0 = (size_t)(kbase + wave * 16 + l16) * 32 + q * 8;
    const size_t vst0 = (size_t)((wave & 1) * 16 + l16) * NTOT + kbase +
                        (wave >> 1) * 32 + q * 8;
    const int kds = wave * 512 + lane * 8;
    const int vds = wave * 512 + (q & 1) * 256 + l16 * 8 + (q >> 1) * 4;
    const int frd = lane * 8;           // fragment read offset within region

    f32x4 o[4][2];
    #pragma unroll
    for (int g = 0; g < 4; ++g) {
        o[g][0] = (f32x4){0,0,0,0};
        o[g][1] = (f32x4){0,0,0,0};
    }
    const f32x4 zero = {0,0,0,0};
    float lp[4] = {0.f, 0.f, 0.f, 0.f};

    for (int half = 0; half < 2; ++half) {
        // ---- stage 512-k slice (8 tiles) ----
        if (half)
            __syncthreads();            // all waves done reading previous slice
        {
            const size_t kst = kst0 + (size_t)(half * 512) * 32;
            const size_t vst = vst0 + half * 512;
            #pragma unroll
            for (int m = 0; m < 8; ++m) {
                uint4 kr = *(const uint4*)(Kbh + kst + m * 2048);
                uint4 vr = *(const uint4*)(Vg + vst + m * 64);
                *(uint4*)(&Ksh[m * 2048 + kds]) = kr;
                uint2 va = {vr.x, vr.y};
                uint2 vb = {vr.z, vr.w};
                *(uint2*)(&Vsh[m * 2048 + vds])       = va;
                *(uint2*)(&Vsh[m * 2048 + vds + 128]) = vb;
            }
        }
        __syncthreads();

        bf16x8 ak[4], av[4];
        #pragma unroll
        for (int t = 0; t < 4; ++t) {
            ak[t] = *(const bf16x8*)(&Ksh[t * 512 + frd]);
            av[t] = *(const bf16x8*)(&Vsh[t * 512 + frd]);
        }

        for (int m = 0; m < 8; ++m) {
            bf16x8 nak[4], nav[4];
            if (m < 7) {
                const int nb = (m + 1) * 2048;
                #pragma unroll
                for (int t = 0; t < 4; ++t) {
                    nak[t] = *(const bf16x8*)(&Ksh[nb + t * 512 + frd]);
                    nav[t] = *(const bf16x8*)(&Vsh[nb + t * 512 + frd]);
                }
            }
            // S for all 4 q-groups (K fragments shared)
            f32x4 s[4][4];
            #pragma unroll
            for (int t = 0; t < 4; ++t) {
                #pragma unroll
                for (int g = 0; g < 4; ++g)
                    s[g][t] = __builtin_amdgcn_mfma_f32_16x16x32_bf16(ak[t], bq[g], zero, 0, 0, 0);
            }
            // per group: exp2 -> pack in-register -> PV (no LDS round-trip)
            #pragma unroll
            for (int g = 0; g < 4; ++g) {
                float e[4][4];
                #pragma unroll
                for (int t = 0; t < 4; ++t) {
                    e[t][0] = __builtin_amdgcn_exp2f(s[g][t][0]);
                    e[t][1] = __builtin_amdgcn_exp2f(s[g][t][1]);
                    e[t][2] = __builtin_amdgcn_exp2f(s[g][t][2]);
                    e[t][3] = __builtin_amdgcn_exp2f(s[g][t][3]);
                    lp[g] += (e[t][0] + e[t][1]) + (e[t][2] + e[t][3]);
                }
                uint4 u0 = {pkbf(e[0][0], e[0][1]), pkbf(e[0][2], e[0][3]),
                            pkbf(e[1][0], e[1][1]), pkbf(e[1][2], e[1][3])};
                uint4 u1 = {pkbf(e[2][0], e[2][1]), pkbf(e[2][2], e[2][3]),
                            pkbf(e[3][0], e[3][1]), pkbf(e[3][2], e[3][3])};
                bf16x8 pb0, pb1;
                __builtin_memcpy(&pb0, &u0, 16);
                __builtin_memcpy(&pb1, &u1, 16);
                o[g][0] = __builtin_amdgcn_mfma_f32_16x16x32_bf16(av[0], pb0, o[g][0], 0, 0, 0);
                o[g][1] = __builtin_amdgcn_mfma_f32_16x16x32_bf16(av[1], pb0, o[g][1], 0, 0, 0);
                o[g][0] = __builtin_amdgcn_mfma_f32_16x16x32_bf16(av[2], pb1, o[g][0], 0, 0, 0);
                o[g][1] = __builtin_amdgcn_mfma_f32_16x16x32_bf16(av[3], pb1, o[g][1], 0, 0, 0);
            }
            if (m < 7) {
                #pragma unroll
                for (int t = 0; t < 4; ++t) { ak[t] = nak[t]; av[t] = nav[t]; }
            }
        }
    }

    #pragma unroll
    for (int g = 0; g < 4; ++g) {
        lp[g] += __shfl_xor(lp[g], 16);
        lp[g] += __shfl_xor(lp[g], 32);
        const size_t ob = ((size_t)(kc * 8 + bh) * NTOT + q0w + g * 16 + l16) * 32 + q * 4;
        uint2 w0 = {pkbf(o[g][0][0], o[g][0][1]), pkbf(o[g][0][2], o[g][0][3])};
        uint2 w1 = {pkbf(o[g][1][0], o[g][1][1]), pkbf(o[g][1][2], o[g][1][3])};
        *(uint2*)(pO + ob)      = w0;
        *(uint2*)(pO + ob + 16) = w1;
        if (q == 0)
            pL[(size_t)(kc * 8 + bh) * NTOT + q0w + g * 16 + l16] = lp[g];
    }
}

// ---------------------------------------------------------------------------
// Kernel 3: fused combine (4 kc partials) + out-projection + bias + residual
// -> res fp32, plus partial sum/sumsq. grid (64 nt, 2 ct64, 2 b), block 256.
// Wo cast fp32->bf16 folded into LDS staging. NO grid barrier (round-1
// lesson: device-scope single-line barrier across 8 XCDs costs ~40 us).
// ---------------------------------------------------------------------------
__global__ __launch_bounds__(256, 4) void outproj_kernel(
    const float* __restrict__ xq,
    const u16* __restrict__ pO, const float* __restrict__ pL,
    const float* __restrict__ Wo, const float* __restrict__ bo,
    float* __restrict__ res, float* __restrict__ partS, float* __restrict__ partQ)
{
    const int nt = blockIdx.x, ct = blockIdx.y, b = blockIdx.z;
    const int n0 = nt * 64;
    const int tid = threadIdx.x;

    __shared__ u16 Xt[64 * 128];        // combined attn tile [n][ci], swizzled
    __shared__ u16 Wl[64 * 136];        // Wo rows ct*64.., pad stride 136

    #pragma unroll
    for (int k = 0; k < 4; ++k) {
        int cid = tid + k * 256;
        int n = cid >> 4;               // 0..63
        int ch = cid & 15;              // ci-chunk: h = ch>>2, d0 = (ch&3)*8
        int bh = b * 4 + (ch >> 2);
        int d0 = (ch & 3) * 8;
        float l = 0.f;
        float v[8];
        #pragma unroll
        for (int j = 0; j < 8; ++j) v[j] = 0.f;
        #pragma unroll
        for (int kcc = 0; kcc < 4; ++kcc) {
            const size_t nrow = (size_t)(kcc * 8 + bh) * NTOT + n0 + n;
            l += pL[nrow];
            uint4 u = *(const uint4*)(pO + nrow * 32 + d0);
            const u32 uu[4] = {u.x, u.y, u.z, u.w};
            #pragma unroll
            for (int j = 0; j < 4; ++j) {
                v[2 * j]     += bf2f((u16)(uu[j] & 0xffffu));
                v[2 * j + 1] += bf2f((u16)(uu[j] >> 16));
            }
        }
        const float inv = 1.0f / l;
        uint4 vv = {pkbf(v[0] * inv, v[1] * inv), pkbf(v[2] * inv, v[3] * inv),
                    pkbf(v[4] * inv, v[5] * inv), pkbf(v[6] * inv, v[7] * inv)};
        *(uint4*)(Xt + n * 128 + ((ch ^ (n & 7)) * 8)) = vv;
    }
    // stage Wo rows ct*64..ct*64+63 fp32 -> bf16: 64 rows x 16 chunks
    #pragma unroll
    for (int k = 0; k < 4; ++k) {
        int id = tid + k * 256;         // 0..1023
        int row = id >> 4;              // 0..63
        int off = (id & 15) * 8;        // 0..120
        const float* wsrc = Wo + (size_t)(ct * 64 + row) * 128 + off;
        float4 wa = *(const float4*)(wsrc);
        float4 wc = *(const float4*)(wsrc + 4);
        uint4 vv = {pkbf(wa.x, wa.y), pkbf(wa.z, wa.w),
                    pkbf(wc.x, wc.y), pkbf(wc.z, wc.w)};
        *(uint4*)(Wl + row * 136 + off) = vv;
    }
    __syncthreads();

    const int wave = tid >> 6, lane = tid & 63;
    const int quad = lane >> 4, l16 = lane & 15;
    f32x4 acc[4];
    #pragma unroll
    for (int cf = 0; cf < 4; ++cf) acc[cf] = (f32x4){0.f, 0.f, 0.f, 0.f};

    #pragma unroll
    for (int kk = 0; kk < 4; ++kk) {
        bf16x8 bx = *(const bf16x8*)(Xt + (wave * 16 + l16) * 128 +
                                     (((kk * 4 + quad) ^ (l16 & 7)) * 8));
        #pragma unroll
        for (int cf = 0; cf < 4; ++cf) {
            bf16x8 aw = *(const bf16x8*)(Wl + (cf * 16 + l16) * 136 + kk * 32 + quad * 8);
            acc[cf] = __builtin_amdgcn_mfma_f32_16x16x32_bf16(aw, bx, acc[cf], 0, 0, 0);
        }
    }

    const int n = n0 + wave * 16 + l16;
    const int tile = nt * 4 + wave;
    #pragma unroll
    for (int cf = 0; cf < 4; ++cf) {
        float4 b4 = *(const float4*)(bo + ct * 64 + cf * 16 + quad * 4);
        const float bb[4] = {b4.x, b4.y, b4.z, b4.w};
        float sv[4], qv[4];
        #pragma unroll
        for (int r = 0; r < 4; ++r) {
            int c = ct * 64 + cf * 16 + quad * 4 + r;
            float v = acc[cf][r] + bb[r] + xq[(size_t)(b * CCH + c) * NTOT + n];
            res[(size_t)(b * CCH + c) * NTOT + n] = v;
            sv[r] = v;
            qv[r] = v * v;
        }
        #pragma unroll
        for (int off = 1; off < 16; off <<= 1) {
            #pragma unroll
            for (int r = 0; r < 4; ++r) {
                sv[r] += __shfl_xor(sv[r], off);
                qv[r] += __shfl_xor(qv[r], off);
            }
        }
        if (l16 == 0) {
            #pragma unroll
            for (int r = 0; r < 4; ++r) {
                int c = ct * 64 + cf * 16 + quad * 4 + r;
                partS[(size_t)(b * CCH + c) * 256 + tile] = sv[r];
                partQ[(size_t)(b * CCH + c) * 256 + tile] = qv[r];
            }
        }
    }
}

// ---------------------------------------------------------------------------
// Kernel 4: reduce partials, InstanceNorm, fp32 store. grid (128, 2).
// ---------------------------------------------------------------------------
__global__ __launch_bounds__(256) void norm_kernel(
    const float* __restrict__ res, const float* __restrict__ partS,
    const float* __restrict__ partQ, float* __restrict__ out)
{
    const int c = blockIdx.x, b = blockIdx.y;
    const int tid = threadIdx.x;
    const size_t row = (size_t)(b * CCH + c);
    __shared__ float rs[4], rq[4];
    float s = partS[row * 256 + tid];
    float q = partQ[row * 256 + tid];
    #pragma unroll
    for (int off = 1; off < 64; off <<= 1) {
        s += __shfl_xor(s, off);
        q += __shfl_xor(q, off);
    }
    const int wv = tid >> 6, ln = tid & 63;
    if (ln == 0) { rs[wv] = s; rq[wv] = q; }
    __syncthreads();
    float ts = rs[0] + rs[1] + rs[2] + rs[3];
    float tq = rq[0] + rq[1] + rq[2] + rq[3];
    float mu  = ts * (1.0f / 4096.0f);
    float var = tq * (1.0f / 4096.0f) - mu * mu;
    float inv = rsqrtf(var + 1e-5f);
    const size_t base = row * NTOT;
    #pragma unroll
    for (int j = 0; j < 4; ++j) {
        int n = tid * 4 + j * 1024;
        float4 v = *(const float4*)(res + base + n);
        float4 o;
        o.x = (v.x - mu) * inv; o.y = (v.y - mu) * inv;
        o.z = (v.z - mu) * inv; o.w = (v.w - mu) * inv;
        *(float4*)(out + base + n) = o;
    }
}

extern "C" void kernel_launch(void* const* d_in, const int* in_sizes, int n_in,
                              void* d_out, int out_size, void* d_ws, size_t ws_size,
                              hipStream_t stream)
{
    const float* xq  = (const float*)d_in[0];
    const float* xkv = (const float*)d_in[1];
    const float* Wq  = (const float*)d_in[2];
    const float* bq  = (const float*)d_in[3];
    const float* Wk  = (const float*)d_in[4];
    const float* bk  = (const float*)d_in[5];
    const float* Wv  = (const float*)d_in[6];
    const float* bv  = (const float*)d_in[7];
    const float* Wo  = (const float*)d_in[8];
    const float* bo  = (const float*)d_in[9];
    float* out = (float*)d_out;

    char* ws = (char*)d_ws;
    const size_t MB = (size_t)1 << 20;
    u16* Qt = (u16*)(ws + 0 * MB);            // 2 MB [bh][n][d]
    u16* Kt = (u16*)(ws + 2 * MB);            // 2 MB
    u16* Vn = (u16*)(ws + 4 * MB);            // 2 MB [b*128+c][n]
    u16* pO = (u16*)(ws + 6 * MB);            // 8 MB [kc4][bh][n][d]
    float* pL = (float*)(ws + 14 * MB);       // 512 KB [kc4][bh][n]
    float* res   = (float*)(ws + 16 * MB);    // 4 MB
    float* partS = (float*)(ws + 20 * MB);            // 256 KB
    float* partQ = (float*)(ws + 20 * MB + 262144);   // 256 KB

    proj_kernel<<<dim3(64, 3, 2), 256, 0, stream>>>(xq, xkv, Wq, bq, Wk, bk, Wv, bv, Qt, Kt, Vn);
    flash_attn_kernel<<<dim3(16, 4, 8), 256, 0, stream>>>(Qt, Kt, Vn, pO, pL);
    outproj_kernel<<<dim3(64, 2, 2), 256, 0, stream>>>(xq, pO, pL, Wo, bo, res, partS, partQ);
    norm_kernel<<<dim3(128, 2), 256, 0, stream>>>(res, partS, partQ, out);
}